// Round 4
// baseline (29.066 us; speedup 1.0000x reference)
//
#include <hip/hip_runtime.h>

// Depthwise causal FIR conv1d.
// x: (B, L, H, D) fp32, filters: (H, D, K) fp32, y: (B, L, H, D) fp32
// y[b,l,c] = sum_k filt[c,k] * x[b, l-6+k, c]   (zero-padded for l-6+k < 0)
// C = H*D = 1024 contiguous innermost -> vectorize channels as 4-wide vectors.
// A/B round: LCHUNK=16 (4 waves/SIMD) with PLAIN stores (nt removed).
//   ~24us -> TLP helps, nt was the R3 regression
//   ~29us -> chunk split itself regressed; revert to 32 next

typedef float f32x4 __attribute__((ext_vector_type(4)));

constexpr int B_ = 4;
constexpr int L_ = 4096;
constexpr int H_ = 16;
constexpr int D_ = 64;
constexpr int K_ = 7;
constexpr int C_ = H_ * D_;      // 1024
constexpr int C4_ = C_ / 4;      // 256 channel-groups of 4
constexpr int LCHUNK = 16;       // L rows per block
constexpr int NCHUNK = L_ / LCHUNK;  // 256

__global__ __launch_bounds__(256)
void dwfir_kernel(const float* __restrict__ x,
                  const float* __restrict__ filt,
                  float* __restrict__ y) {
    const int c4 = threadIdx.x;              // 0..255 -> channels 4*c4 .. 4*c4+3
    const int chunk = blockIdx.x;            // 0 .. B_*NCHUNK-1
    const int b  = chunk / NCHUNK;
    const int l0 = (chunk % NCHUNK) * LCHUNK;

    // ---- filters: 28 consecutive floats per thread (channel-major [c][k]),
    //      112 B per thread, 16B-aligned -> 7 vec4 loads, static unpack.
    const f32x4* fv = reinterpret_cast<const f32x4*>(filt) + c4 * 7;
    float ff[28];
    #pragma unroll
    for (int i = 0; i < 7; ++i) {
        f32x4 t = fv[i];
        ff[4 * i + 0] = t.x;
        ff[4 * i + 1] = t.y;
        ff[4 * i + 2] = t.z;
        ff[4 * i + 3] = t.w;
    }
    // ff[ch*7 + k] = filt[4*c4 + ch][k]

    const f32x4* xv = reinterpret_cast<const f32x4*>(x);
    f32x4*       yv = reinterpret_cast<f32x4*>(y);

    // ---- preload sliding window: w[j] = x[b, l0-6+j, :] for j=0..5
    f32x4 w[7];
    #pragma unroll
    for (int j = 0; j < 6; ++j) {
        const int l = l0 - 6 + j;
        if (l >= 0) {
            w[j] = xv[(size_t)(b * L_ + l) * C4_ + c4];
        } else {
            w[j] = (f32x4)(0.f);
        }
    }

    // ---- main loop; all indices static under full unroll
    #pragma unroll
    for (int i = 0; i < LCHUNK; ++i) {
        const int l = l0 + i;
        const size_t off = (size_t)(b * L_ + l) * C4_ + c4;
        w[6] = xv[off];

        f32x4 acc;
        acc.x = ff[0]  * w[0].x;
        acc.y = ff[7]  * w[0].y;
        acc.z = ff[14] * w[0].z;
        acc.w = ff[21] * w[0].w;
        #pragma unroll
        for (int k = 1; k < 7; ++k) {
            acc.x = fmaf(ff[k],      w[k].x, acc.x);
            acc.y = fmaf(ff[7 + k],  w[k].y, acc.y);
            acc.z = fmaf(ff[14 + k], w[k].z, acc.z);
            acc.w = fmaf(ff[21 + k], w[k].w, acc.w);
        }
        yv[off] = acc;

        #pragma unroll
        for (int j = 0; j < 6; ++j) w[j] = w[j + 1];
    }
}

extern "C" void kernel_launch(void* const* d_in, const int* in_sizes, int n_in,
                              void* d_out, int out_size, void* d_ws, size_t ws_size,
                              hipStream_t stream) {
    const float* x    = (const float*)d_in[0];
    const float* filt = (const float*)d_in[1];
    float*       y    = (float*)d_out;

    dim3 grid(B_ * NCHUNK);   // 1024 blocks
    dim3 block(256);
    dwfir_kernel<<<grid, block, 0, stream>>>(x, filt, y);
}

// Round 5
// 27.532 us; speedup vs baseline: 1.0557x; 1.0557x over previous
//
#include <hip/hip_runtime.h>

// Depthwise causal FIR conv1d.
// x: (B, L, H, D) fp32, filters: (H, D, K) fp32, y: (B, L, H, D) fp32
// y[b,l,c] = sum_k filt[c,k] * x[b, l-6+k, c]   (zero-padded for l-6+k < 0)
// C = H*D = 1024 contiguous innermost -> vectorize channels as 4-wide vectors.
// R5: LCHUNK=64 -> 256 blocks = 1 block/CU, halo amortized to 1.09x.
// History: LCHUNK=32 -> 26.9us, LCHUNK=16 -> 29.1us (time tracks per-output
// VMEM instruction count, not TLP). Plain stores (nt-store was neutral).

typedef float f32x4 __attribute__((ext_vector_type(4)));

constexpr int B_ = 4;
constexpr int L_ = 4096;
constexpr int H_ = 16;
constexpr int D_ = 64;
constexpr int K_ = 7;
constexpr int C_ = H_ * D_;      // 1024
constexpr int C4_ = C_ / 4;      // 256 channel-groups of 4
constexpr int LCHUNK = 64;       // L rows per block
constexpr int NCHUNK = L_ / LCHUNK;  // 64

__global__ __launch_bounds__(256)
void dwfir_kernel(const float* __restrict__ x,
                  const float* __restrict__ filt,
                  float* __restrict__ y) {
    const int c4 = threadIdx.x;              // 0..255 -> channels 4*c4 .. 4*c4+3
    const int chunk = blockIdx.x;            // 0 .. B_*NCHUNK-1
    const int b  = chunk / NCHUNK;
    const int l0 = (chunk % NCHUNK) * LCHUNK;

    // ---- filters: 28 consecutive floats per thread (channel-major [c][k]),
    //      112 B per thread, 16B-aligned -> 7 vec4 loads, static unpack.
    const f32x4* fv = reinterpret_cast<const f32x4*>(filt) + c4 * 7;
    float ff[28];
    #pragma unroll
    for (int i = 0; i < 7; ++i) {
        f32x4 t = fv[i];
        ff[4 * i + 0] = t.x;
        ff[4 * i + 1] = t.y;
        ff[4 * i + 2] = t.z;
        ff[4 * i + 3] = t.w;
    }
    // ff[ch*7 + k] = filt[4*c4 + ch][k]

    const f32x4* xv = reinterpret_cast<const f32x4*>(x);
    f32x4*       yv = reinterpret_cast<f32x4*>(y);

    // ---- preload sliding window: w[j] = x[b, l0-6+j, :] for j=0..5
    f32x4 w[7];
    #pragma unroll
    for (int j = 0; j < 6; ++j) {
        const int l = l0 - 6 + j;
        if (l >= 0) {
            w[j] = xv[(size_t)(b * L_ + l) * C4_ + c4];
        } else {
            w[j] = (f32x4)(0.f);
        }
    }

    // ---- main loop; all indices static under full unroll
    #pragma unroll
    for (int i = 0; i < LCHUNK; ++i) {
        const int l = l0 + i;
        const size_t off = (size_t)(b * L_ + l) * C4_ + c4;
        w[6] = xv[off];

        f32x4 acc;
        acc.x = ff[0]  * w[0].x;
        acc.y = ff[7]  * w[0].y;
        acc.z = ff[14] * w[0].z;
        acc.w = ff[21] * w[0].w;
        #pragma unroll
        for (int k = 1; k < 7; ++k) {
            acc.x = fmaf(ff[k],      w[k].x, acc.x);
            acc.y = fmaf(ff[7 + k],  w[k].y, acc.y);
            acc.z = fmaf(ff[14 + k], w[k].z, acc.z);
            acc.w = fmaf(ff[21 + k], w[k].w, acc.w);
        }
        yv[off] = acc;

        #pragma unroll
        for (int j = 0; j < 6; ++j) w[j] = w[j + 1];
    }
}

extern "C" void kernel_launch(void* const* d_in, const int* in_sizes, int n_in,
                              void* d_out, int out_size, void* d_ws, size_t ws_size,
                              hipStream_t stream) {
    const float* x    = (const float*)d_in[0];
    const float* filt = (const float*)d_in[1];
    float*       y    = (float*)d_out;

    dim3 grid(B_ * NCHUNK);   // 256 blocks, 1 per CU
    dim3 block(256);
    dwfir_kernel<<<grid, block, 0, stream>>>(x, filt, y);
}

// Round 6
// 26.843 us; speedup vs baseline: 1.0828x; 1.0257x over previous
//
#include <hip/hip_runtime.h>

// Depthwise causal FIR conv1d.
// x: (B, L, H, D) fp32, filters: (H, D, K) fp32, y: (B, L, H, D) fp32
// y[b,l,c] = sum_k filt[c,k] * x[b, l-6+k, c]   (zero-padded for l-6+k < 0)
// C = H*D = 1024 contiguous innermost -> vectorize channels as 4-wide vectors.
//
// Tuning history (measured):
//   LCHUNK=32, 512 blk:  26.91 us   <- champion
//   LCHUNK=16, 1024 blk: 29.06 us   (halo/instr overhead dominates; nt-store neutral)
//   LCHUNK=64, 256 blk:  27.53 us   (1 wave/SIMD latency-exposed)
// R6: champion + XCD-aware chunk swizzle: adjacent L-chunks (sharing 6 halo
// rows fetched concurrently) land on the SAME XCD -> halo reads hit local L2
// instead of L3. 512 % 8 == 0 so the swizzle is bijective.

typedef float f32x4 __attribute__((ext_vector_type(4)));

constexpr int B_ = 4;
constexpr int L_ = 4096;
constexpr int H_ = 16;
constexpr int D_ = 64;
constexpr int K_ = 7;
constexpr int C_ = H_ * D_;      // 1024
constexpr int C4_ = C_ / 4;      // 256 channel-groups of 4
constexpr int LCHUNK = 32;       // L rows per block
constexpr int NCHUNK = L_ / LCHUNK;  // 128
constexpr int NBLK = B_ * NCHUNK;    // 512
constexpr int NXCD = 8;
constexpr int PER_XCD = NBLK / NXCD; // 64

__global__ __launch_bounds__(256)
void dwfir_kernel(const float* __restrict__ x,
                  const float* __restrict__ filt,
                  float* __restrict__ y) {
    const int c4 = threadIdx.x;              // 0..255 -> channels 4*c4 .. 4*c4+3
    // XCD swizzle: hardware assigns blockIdx round-robin across 8 XCDs.
    // chunk = (bid%8)*64 + bid/8 gives each XCD a contiguous run of 64 chunks.
    const int bid = blockIdx.x;
    const int chunk = (bid & (NXCD - 1)) * PER_XCD + (bid >> 3);
    const int b  = chunk / NCHUNK;
    const int l0 = (chunk % NCHUNK) * LCHUNK;

    // ---- filters: 28 consecutive floats per thread (channel-major [c][k]),
    //      112 B per thread, 16B-aligned -> 7 vec4 loads, static unpack.
    const f32x4* fv = reinterpret_cast<const f32x4*>(filt) + c4 * 7;
    float ff[28];
    #pragma unroll
    for (int i = 0; i < 7; ++i) {
        f32x4 t = fv[i];
        ff[4 * i + 0] = t.x;
        ff[4 * i + 1] = t.y;
        ff[4 * i + 2] = t.z;
        ff[4 * i + 3] = t.w;
    }
    // ff[ch*7 + k] = filt[4*c4 + ch][k]

    const f32x4* xv = reinterpret_cast<const f32x4*>(x);
    f32x4*       yv = reinterpret_cast<f32x4*>(y);

    // ---- preload sliding window: w[j] = x[b, l0-6+j, :] for j=0..5
    f32x4 w[7];
    #pragma unroll
    for (int j = 0; j < 6; ++j) {
        const int l = l0 - 6 + j;
        if (l >= 0) {
            w[j] = xv[(size_t)(b * L_ + l) * C4_ + c4];
        } else {
            w[j] = (f32x4)(0.f);
        }
    }

    // ---- main loop; all indices static under full unroll
    #pragma unroll
    for (int i = 0; i < LCHUNK; ++i) {
        const int l = l0 + i;
        const size_t off = (size_t)(b * L_ + l) * C4_ + c4;
        w[6] = xv[off];

        f32x4 acc;
        acc.x = ff[0]  * w[0].x;
        acc.y = ff[7]  * w[0].y;
        acc.z = ff[14] * w[0].z;
        acc.w = ff[21] * w[0].w;
        #pragma unroll
        for (int k = 1; k < 7; ++k) {
            acc.x = fmaf(ff[k],      w[k].x, acc.x);
            acc.y = fmaf(ff[7 + k],  w[k].y, acc.y);
            acc.z = fmaf(ff[14 + k], w[k].z, acc.z);
            acc.w = fmaf(ff[21 + k], w[k].w, acc.w);
        }
        yv[off] = acc;

        #pragma unroll
        for (int j = 0; j < 6; ++j) w[j] = w[j + 1];
    }
}

extern "C" void kernel_launch(void* const* d_in, const int* in_sizes, int n_in,
                              void* d_out, int out_size, void* d_ws, size_t ws_size,
                              hipStream_t stream) {
    const float* x    = (const float*)d_in[0];
    const float* filt = (const float*)d_in[1];
    float*       y    = (float*)d_out;

    dim3 grid(NBLK);    // 512 blocks
    dim3 block(256);
    dwfir_kernel<<<grid, block, 0, stream>>>(x, filt, y);
}

// Round 7
// 25.792 us; speedup vs baseline: 1.1269x; 1.0407x over previous
//
#include <hip/hip_runtime.h>

// Depthwise causal FIR conv1d.
// x: (B, L, H, D) fp32, filters: (H, D, K) fp32, y: (B, L, H, D) fp32
// y[b,l,c] = sum_k filt[c,k] * x[b, l-6+k, c]   (zero-padded for l-6+k < 0)
// C = H*D = 1024 contiguous innermost -> vectorize channels as 4-wide vectors.
//
// Tuning history (measured):
//   LCHUNK=32, 512 blk:          26.91 us  <- base champion
//   LCHUNK=16, 1024 blk:         29.06 us  (halo/instr overhead; nt-store neutral)
//   LCHUNK=64, 256 blk:          27.53 us  (1 wave/SIMD latency-exposed)
//   + XCD swizzle:               26.84 us  (neutral)
// R7: explicit 8-row software pipeline — batch-issue 8 independent row loads
// ahead of each 8-output compute group. Same instruction count, same TLP;
// raises guaranteed loads-in-flight per thread. Tests whether the 5.0 vs
// 6.3 TB/s copy-ceiling gap is MLP/latency exposure.

typedef float f32x4 __attribute__((ext_vector_type(4)));

constexpr int B_ = 4;
constexpr int L_ = 4096;
constexpr int H_ = 16;
constexpr int D_ = 64;
constexpr int K_ = 7;
constexpr int C_ = H_ * D_;      // 1024
constexpr int C4_ = C_ / 4;      // 256 channel-groups of 4
constexpr int LCHUNK = 32;       // L rows per block
constexpr int NCHUNK = L_ / LCHUNK;  // 128
constexpr int NBLK = B_ * NCHUNK;    // 512
constexpr int NXCD = 8;
constexpr int PER_XCD = NBLK / NXCD; // 64
constexpr int NROWS = LCHUNK + K_ - 1;  // 38 rows needed per chunk

__global__ __launch_bounds__(256)
void dwfir_kernel(const float* __restrict__ x,
                  const float* __restrict__ filt,
                  float* __restrict__ y) {
    const int c4 = threadIdx.x;              // 0..255 -> channels 4*c4 .. 4*c4+3
    const int bid = blockIdx.x;
    const int chunk = (bid & (NXCD - 1)) * PER_XCD + (bid >> 3);
    const int b  = chunk / NCHUNK;
    const int l0 = (chunk % NCHUNK) * LCHUNK;

    // ---- filters: 28 consecutive floats per thread (channel-major [c][k])
    const f32x4* fv = reinterpret_cast<const f32x4*>(filt) + c4 * 7;
    float ff[28];
    #pragma unroll
    for (int i = 0; i < 7; ++i) {
        f32x4 t = fv[i];
        ff[4 * i + 0] = t.x;
        ff[4 * i + 1] = t.y;
        ff[4 * i + 2] = t.z;
        ff[4 * i + 3] = t.w;
    }
    // ff[ch*7 + k] = filt[4*c4 + ch][k]

    const f32x4* xv = reinterpret_cast<const f32x4*>(x);
    f32x4*       yv = reinterpret_cast<f32x4*>(y);

    // row i (i=0..37) lives at global L-index l0-6+i
    const f32x4* xrow = xv + (size_t)(b * L_ + l0 - 6) * C4_ + c4;
    f32x4*       yrow = yv + (size_t)(b * L_ + l0) * C4_ + c4;

    f32x4 row[NROWS];   // fully statically indexed -> registers

    // ---- prologue: prefetch rows 0..13 (6 halo + first compute batch)
    if (l0 >= 6) {       // uniform branch; true for 508/512 blocks
        #pragma unroll
        for (int i = 0; i < 14; ++i)
            row[i] = xrow[(size_t)i * C4_];
    } else {             // l0 == 0 blocks: zero-pad the left halo
        #pragma unroll
        for (int i = 0; i < 14; ++i) {
            const int l = l0 - 6 + i;
            if (l >= 0) row[i] = xrow[(size_t)i * C4_];
            else        row[i] = (f32x4)(0.f);
        }
    }

    // ---- pipelined main: issue next 8 loads, then compute 8 outputs
    #pragma unroll
    for (int g = 0; g < 4; ++g) {
        if (g < 3) {
            #pragma unroll
            for (int i = 0; i < 8; ++i)
                row[14 + 8 * g + i] = xrow[(size_t)(14 + 8 * g + i) * C4_];
        }
        #pragma unroll
        for (int j = 8 * g; j < 8 * g + 8; ++j) {
            f32x4 acc;
            acc.x = ff[0]  * row[j].x;
            acc.y = ff[7]  * row[j].y;
            acc.z = ff[14] * row[j].z;
            acc.w = ff[21] * row[j].w;
            #pragma unroll
            for (int k = 1; k < 7; ++k) {
                acc.x = fmaf(ff[k],      row[j + k].x, acc.x);
                acc.y = fmaf(ff[7 + k],  row[j + k].y, acc.y);
                acc.z = fmaf(ff[14 + k], row[j + k].z, acc.z);
                acc.w = fmaf(ff[21 + k], row[j + k].w, acc.w);
            }
            yrow[(size_t)j * C4_] = acc;
        }
    }
}

extern "C" void kernel_launch(void* const* d_in, const int* in_sizes, int n_in,
                              void* d_out, int out_size, void* d_ws, size_t ws_size,
                              hipStream_t stream) {
    const float* x    = (const float*)d_in[0];
    const float* filt = (const float*)d_in[1];
    float*       y    = (float*)d_out;

    dim3 grid(NBLK);    // 512 blocks
    dim3 block(256);
    dwfir_kernel<<<grid, block, 0, stream>>>(x, filt, y);
}

// Round 8
// 25.207 us; speedup vs baseline: 1.1531x; 1.0232x over previous
//
#include <hip/hip_runtime.h>

// Depthwise causal FIR conv1d.
// x: (B, L, H, D) fp32, filters: (H, D, K) fp32, y: (B, L, H, D) fp32
// y[b,l,c] = sum_k filt[c,k] * x[b, l-6+k, c]   (zero-padded for l-6+k < 0)
// C = H*D = 1024 contiguous innermost -> vectorize channels as 4-wide vectors.
//
// Tuning history (measured):
//   LCHUNK=32, 512 blk:          26.91 us
//   LCHUNK=16, 1024 blk:         29.06 us  (halo/instr overhead; nt-store neutral)
//   LCHUNK=64, 256 blk:          27.53 us  (1 wave/SIMD latency-exposed)
//   + XCD swizzle:               26.84 us  (neutral)
//   + 8-row load pipeline:       25.79 us  (MLP exposure confirmed, partial)
// R8: full-depth prefetch — issue ALL 38 row loads in one burst, then all 32
// compute+stores. ~190 VGPR (<256, occupancy grid-limited at 2 blk/CU anyway).
// Max per-thread loads-in-flight 8 -> 38.

typedef float f32x4 __attribute__((ext_vector_type(4)));

constexpr int B_ = 4;
constexpr int L_ = 4096;
constexpr int H_ = 16;
constexpr int D_ = 64;
constexpr int K_ = 7;
constexpr int C_ = H_ * D_;      // 1024
constexpr int C4_ = C_ / 4;      // 256 channel-groups of 4
constexpr int LCHUNK = 32;       // L rows per block
constexpr int NCHUNK = L_ / LCHUNK;  // 128
constexpr int NBLK = B_ * NCHUNK;    // 512
constexpr int NXCD = 8;
constexpr int PER_XCD = NBLK / NXCD; // 64
constexpr int NROWS = LCHUNK + K_ - 1;  // 38 rows per chunk

__global__ __launch_bounds__(256)
void dwfir_kernel(const float* __restrict__ x,
                  const float* __restrict__ filt,
                  float* __restrict__ y) {
    const int c4 = threadIdx.x;              // 0..255 -> channels 4*c4 .. 4*c4+3
    const int bid = blockIdx.x;
    const int chunk = (bid & (NXCD - 1)) * PER_XCD + (bid >> 3);
    const int b  = chunk / NCHUNK;
    const int l0 = (chunk % NCHUNK) * LCHUNK;

    const f32x4* xv = reinterpret_cast<const f32x4*>(x);
    f32x4*       yv = reinterpret_cast<f32x4*>(y);

    // row i (i=0..37) lives at global L-index l0-6+i
    const f32x4* xrow = xv + (size_t)(b * L_ + l0 - 6) * C4_ + c4;
    f32x4*       yrow = yv + (size_t)(b * L_ + l0) * C4_ + c4;

    f32x4 row[NROWS];   // fully statically indexed -> registers

    // ---- full-depth load burst: all 38 rows issued before any compute
    if (l0 >= 6) {       // uniform branch; true for 508/512 blocks
        #pragma unroll
        for (int i = 0; i < NROWS; ++i)
            row[i] = xrow[(size_t)i * C4_];
    } else {             // l0 == 0 blocks: zero-pad the left halo
        #pragma unroll
        for (int i = 0; i < NROWS; ++i) {
            const int l = l0 - 6 + i;
            if (l >= 0) row[i] = xrow[(size_t)i * C4_];
            else        row[i] = (f32x4)(0.f);
        }
    }

    // ---- filters after the row burst (they hit L2 instantly; off the
    //      critical path). 28 consecutive floats per thread.
    const f32x4* fv = reinterpret_cast<const f32x4*>(filt) + c4 * 7;
    float ff[28];
    #pragma unroll
    for (int i = 0; i < 7; ++i) {
        f32x4 t = fv[i];
        ff[4 * i + 0] = t.x;
        ff[4 * i + 1] = t.y;
        ff[4 * i + 2] = t.z;
        ff[4 * i + 3] = t.w;
    }
    // ff[ch*7 + k] = filt[4*c4 + ch][k]

    // ---- compute + store all 32 outputs
    #pragma unroll
    for (int j = 0; j < LCHUNK; ++j) {
        f32x4 acc;
        acc.x = ff[0]  * row[j].x;
        acc.y = ff[7]  * row[j].y;
        acc.z = ff[14] * row[j].z;
        acc.w = ff[21] * row[j].w;
        #pragma unroll
        for (int k = 1; k < 7; ++k) {
            acc.x = fmaf(ff[k],      row[j + k].x, acc.x);
            acc.y = fmaf(ff[7 + k],  row[j + k].y, acc.y);
            acc.z = fmaf(ff[14 + k], row[j + k].z, acc.z);
            acc.w = fmaf(ff[21 + k], row[j + k].w, acc.w);
        }
        yrow[(size_t)j * C4_] = acc;
    }
}

extern "C" void kernel_launch(void* const* d_in, const int* in_sizes, int n_in,
                              void* d_out, int out_size, void* d_ws, size_t ws_size,
                              hipStream_t stream) {
    const float* x    = (const float*)d_in[0];
    const float* filt = (const float*)d_in[1];
    float*       y    = (float*)d_out;

    dim3 grid(NBLK);    // 512 blocks
    dim3 block(256);
    dwfir_kernel<<<grid, block, 0, stream>>>(x, filt, y);
}